// Round 13
// baseline (136.540 us; speedup 1.0000x reference)
//
#include <hip/hip_runtime.h>
#include <hip/hip_bf16.h>

// Problem: B=16, T=S=2048, D=1024, H=24
#define B_ 16
#define T_ 2048
#define S_ 2048
#define D_ 1024
#define H_ 24
#define NROW_ (B_ * T_)            // 32768 rows
#define BS_ (B_ * S_)              // 32768
#define QN32_ ((size_t)NROW_ * 32) // padded projection / h1-part elements

typedef float f32x16 __attribute__((ext_vector_type(16)));
typedef __bf16 bf16x8 __attribute__((ext_vector_type(8)));

union B8u { int4 i; bf16x8 b; };
__device__ inline bf16x8 pun(int4 v) { B8u u; u.i = v; return u.b; }

__device__ inline ushort f2bf(float f) {  // RNE fp32->bf16
  uint u = __float_as_uint(f);
  u += 0x7fffu + ((u >> 16) & 1u);
  return (ushort)(u >> 16);
}
__device__ inline float bf2f(ushort u) { return __uint_as_float(((uint)u) << 16); }

__device__ inline f32x16 mfma32(bf16x8 a, bf16x8 b, f32x16 c) {
  return __builtin_amdgcn_mfma_f32_32x32x16_bf16(a, b, c, 0, 0, 0);
}

__device__ inline uint cvtpk(float a, float b) {
  uint r;
  asm("v_cvt_pk_bf16_f32 %0, %1, %2" : "=v"(r) : "v"(a), "v"(b));
  return r;
}

// ---------------------------------------------------------------------------
// prep_w: pack wq,wk,wv -> global fragment-order bf16 wpk[3][128][24][8].
// ---------------------------------------------------------------------------
__global__ __launch_bounds__(256) void prep_w(
    const float* __restrict__ wq, const float* __restrict__ wk,
    const float* __restrict__ wv, ushort* __restrict__ wpk) {
  int i = blockIdx.x * 256 + threadIdx.x;  // < 3*128*24 = 9216
  if (i >= 3 * 128 * H_) return;
  int which = i / (128 * H_);
  int rem = i - which * 128 * H_;
  int k8g = rem / H_, n = rem - k8g * H_;
  const float* w = (which == 0) ? wq : (which == 1) ? wk : wv;
  ushort t[8];
#pragma unroll
  for (int j = 0; j < 8; ++j) t[j] = f2bf(w[(k8g * 8 + j) * H_ + n]);
  *(int4*)&wpk[(size_t)i * 8] = *(const int4*)t;
}

// ---------------------------------------------------------------------------
// proj (R12): max-depth one-shot staging. R11's grouped pipeline held avg
// ~12-16 loads in flight/wave; here ALL 32 row-loads issue back-to-back
// (128 VGPR of data, static indices) before any ds_write -> vmcnt ramps to
// 32 and drains progressively through the write pass. If the ~2.7 TB/s read
// plateau is per-wave-MLP-bound, this roughly doubles the read rate.
// Everything else identical to R11 (XCD swizzle, swizzled wave-private LDS
// slab, pure-LDS MFMA pass, padded cross-wave reduce, nt-stores in K4).
// ---------------------------------------------------------------------------
#define LOADALL()                                                            \
  float4 gv[32];                                                             \
  _Pragma("unroll") for (int r = 0; r < 32; ++r) gv[r] =                     \
      *(const float4*)(rowp + (size_t)r * D_ + l * 4);
#define WRITEALL()                                                           \
  _Pragma("unroll") for (int r = 0; r < 32; ++r) {                           \
    uint p0 = cvtpk(gv[r].x, gv[r].y), p1 = cvtpk(gv[r].z, gv[r].w);         \
    const int s = (l >> 1) ^ (r & 7);                                        \
    *(uint2*)&sA[w][r][s * 8 + (l & 1) * 4] = make_uint2(p0, p1);            \
  }

__global__ __launch_bounds__(256, 2) void proj_q(
    const float* __restrict__ in, const ushort* __restrict__ wpk,
    ushort* __restrict__ qb) {
  __shared__ __align__(16) ushort sA[4][32][256];  // 64 KiB wave-private bf16

  const int tid = threadIdx.x;
  const int lane = tid & 63, lo = lane & 31, hi = lane >> 5, w = tid >> 6;
  const int l = lane;
  const int bid = (blockIdx.x & 7) * 128 + (blockIdx.x >> 3);  // XCD swizzle
  const long rowbase = (long)bid * 32;
  const int ne = (lo < H_) ? lo : 0;
  const float* rowp = in + rowbase * D_ + w * 256;

  LOADALL();
  WRITEALL();

  int4 bfr[16];
#pragma unroll
  for (int c = 0; c < 16; ++c) {
    const int k8g = w * 32 + 2 * c + hi;
    bfr[c] = *(const int4*)&wpk[(size_t)(k8g * H_ + ne) * 8];
  }
  f32x16 acc = {};
#pragma unroll
  for (int c = 0; c < 16; ++c) {
    const int s = (2 * c + hi) ^ (lo & 7);
    bf16x8 a = pun(*(const int4*)&sA[w][lo][s * 8]);
    acc = mfma32(a, pun(bfr[c]), acc);
  }

  float* sR = (float*)sA;
  __syncthreads();
#pragma unroll
  for (int r = 0; r < 16; ++r) sR[w * 1088 + lane * 17 + r] = acc[r];
  __syncthreads();
  const int qd = tid >> 6, l2 = tid & 63, lo2 = l2 & 31, hi2 = l2 >> 5;
#pragma unroll
  for (int rr = 0; rr < 4; ++rr) {
    const int r = qd * 4 + rr;
    float s = sR[0 * 1088 + l2 * 17 + r] + sR[1 * 1088 + l2 * 17 + r] +
              sR[2 * 1088 + l2 * 17 + r] + sR[3 * 1088 + l2 * 17 + r];
    const int mrow = rr + 8 * qd + 4 * hi2;
    qb[(size_t)(rowbase + mrow) * 32 + lo2] = (lo2 < H_) ? f2bf(s) : (ushort)0;
  }
}

__global__ __launch_bounds__(256, 2) void proj_kv(
    const float* __restrict__ in, const ushort* __restrict__ wpk,
    ushort* __restrict__ kbuf, float* __restrict__ vv) {
  __shared__ __align__(16) ushort sA[4][32][256];  // 64 KiB wave-private bf16

  const int tid = threadIdx.x;
  const int lane = tid & 63, lo = lane & 31, hi = lane >> 5, w = tid >> 6;
  const int l = lane;
  const int bid = (blockIdx.x & 7) * 128 + (blockIdx.x >> 3);  // XCD swizzle
  const long rowbase = (long)bid * 32;
  const int ne = (lo < H_) ? lo : 0;
  const float* rowp = in + rowbase * D_ + w * 256;
  const ushort* wp1 = wpk + (size_t)1 * 128 * H_ * 8;  // wk
  const ushort* wp2 = wpk + (size_t)2 * 128 * H_ * 8;  // wv

  LOADALL();
  WRITEALL();

  int4 bfr1[16], bfr2[16];
#pragma unroll
  for (int c = 0; c < 16; ++c) {
    const int k8g = w * 32 + 2 * c + hi;
    bfr1[c] = *(const int4*)&wp1[(size_t)(k8g * H_ + ne) * 8];
    bfr2[c] = *(const int4*)&wp2[(size_t)(k8g * H_ + ne) * 8];
  }
  f32x16 acc = {};
  f32x16 acc2 = {};
#pragma unroll
  for (int c = 0; c < 16; ++c) {
    const int s = (2 * c + hi) ^ (lo & 7);
    bf16x8 a = pun(*(const int4*)&sA[w][lo][s * 8]);
    acc = mfma32(a, pun(bfr1[c]), acc);
    acc2 = mfma32(a, pun(bfr2[c]), acc2);
  }

  float* sR = (float*)sA;
  __syncthreads();
#pragma unroll
  for (int r = 0; r < 16; ++r) sR[w * 1088 + lane * 17 + r] = acc[r];
  __syncthreads();
  {
    const int qd = tid >> 6, l2 = tid & 63, lo2 = l2 & 31, hi2 = l2 >> 5;
#pragma unroll
    for (int rr = 0; rr < 4; ++rr) {
      const int r = qd * 4 + rr;
      float s = sR[0 * 1088 + l2 * 17 + r] + sR[1 * 1088 + l2 * 17 + r] +
                sR[2 * 1088 + l2 * 17 + r] + sR[3 * 1088 + l2 * 17 + r];
      const int mrow = rr + 8 * qd + 4 * hi2;
      kbuf[(size_t)(rowbase + mrow) * 32 + lo2] =
          (lo2 < H_) ? f2bf(s) : (ushort)0;
    }
  }
  __syncthreads();  // WAR on sR
#pragma unroll
  for (int r = 0; r < 16; ++r) sR[w * 1088 + lane * 17 + r] = acc2[r];
  __syncthreads();
  {
    const int qd = tid >> 6, l2 = tid & 63, lo2 = l2 & 31, hi2 = l2 >> 5;
    if (lo2 < H_) {
#pragma unroll
      for (int rr = 0; rr < 4; ++rr) {
        const int r = qd * 4 + rr;
        float s = sR[0 * 1088 + l2 * 17 + r] + sR[1 * 1088 + l2 * 17 + r] +
                  sR[2 * 1088 + l2 * 17 + r] + sR[3 * 1088 + l2 * 17 + r];
        const int mrow = rr + 8 * qd + 4 * hi2;
        vv[(size_t)(rowbase + mrow) * H_ + lo2] = s;
      }
    }
  }
}
#undef LOADALL
#undef WRITEALL

// ---------------------------------------------------------------------------
// Pass 1 (2 s-tiles/wave): d[b,s] = sum_t exp(q_t.k_s).
// ---------------------------------------------------------------------------
__global__ __launch_bounds__(256) void colsum_mfma(
    const ushort* __restrict__ qb, const ushort* __restrict__ kb,
    float* __restrict__ dpart) {
  __shared__ __align__(16) ushort sQ[4 * 32 * 8];  // [hslot][t][8]
  const int tid = threadIdx.x;
  const int lane = tid & 63;
  const int lo = lane & 31, hi = lane >> 5;
  const int w = tid >> 6;
  const int b = blockIdx.y;
  const int s0 = blockIdx.x * 256 + w * 32;
  const int s1 = s0 + 128;
  const int tpart = blockIdx.z;

  const ushort* krow0 = kb + ((size_t)b * S_ + s0 + lo) * 32;
  bf16x8 k0 = pun(*(const int4*)(krow0 + hi * 8));
  bf16x8 k1 = pun(*(const int4*)(krow0 + 16 + hi * 8));
  const ushort* krow1 = kb + ((size_t)b * S_ + s1 + lo) * 32;
  bf16x8 k2 = pun(*(const int4*)(krow1 + hi * 8));
  bf16x8 k3 = pun(*(const int4*)(krow1 + 16 + hi * 8));

  float dl = 0.f, dl2 = 0.f;
  for (int tc = 0; tc < 16; ++tc) {
    const int tbase = tpart * 512 + tc * 32;
    if (tid < 128) {
      int t = tid >> 2, j = tid & 3;
      *(int4*)&sQ[j * 256 + t * 8] =
          *(const int4*)(qb + ((size_t)b * T_ + tbase + t) * 32 + j * 8);
    }
    __syncthreads();
    bf16x8 qa = pun(*(const int4*)&sQ[hi * 256 + lo * 8]);
    bf16x8 qc = pun(*(const int4*)&sQ[(2 + hi) * 256 + lo * 8]);
    f32x16 c = {};
    c = mfma32(qa, k0, c);
    c = mfma32(qc, k1, c);
#pragma unroll
    for (int r = 0; r < 16; ++r) dl += __expf(c[r]);
    f32x16 c2 = {};
    c2 = mfma32(qa, k2, c2);
    c2 = mfma32(qc, k3, c2);
#pragma unroll
    for (int r = 0; r < 16; ++r) dl2 += __expf(c2[r]);
    __syncthreads();
  }
  dl += __shfl_xor(dl, 32);
  dl2 += __shfl_xor(dl2, 32);
  if (hi == 0) {
    dpart[(size_t)tpart * BS_ + (size_t)b * S_ + s0 + lo] = dl;
    dpart[(size_t)tpart * BS_ + (size_t)b * S_ + s1 + lo] = dl2;
  }
}

// ---------------------------------------------------------------------------
// vscale (dpart reduce folded in): vsT[b][h][s] = bf16(v * 1/d), h pad 32.
// ---------------------------------------------------------------------------
__global__ __launch_bounds__(256) void vscale_kernel(
    const float* __restrict__ vv, const float* __restrict__ dpart,
    ushort* __restrict__ vsT) {
  int gid = blockIdx.x * 256 + threadIdx.x;  // < 16*32*512
  int s4 = gid & 511;
  int h = (gid >> 9) & 31;
  int b = gid >> 14;
  int s0 = s4 * 4;
  ushort4 ov;
  if (h < H_) {
    const float* vp = vv + ((size_t)b * S_ + s0) * H_ + h;
    const float* dp = dpart + (size_t)b * S_ + s0;
    float dv[4];
#pragma unroll
    for (int i = 0; i < 4; ++i) {
      float d = dp[i] + dp[BS_ + i] + dp[2 * BS_ + i] + dp[3 * BS_ + i];
      dv[i] = 1.0f / d;
    }
    ov.x = f2bf(vp[0 * H_] * dv[0]);
    ov.y = f2bf(vp[1 * H_] * dv[1]);
    ov.z = f2bf(vp[2 * H_] * dv[2]);
    ov.w = f2bf(vp[3 * H_] * dv[3]);
  } else {
    ov.x = ov.y = ov.z = ov.w = 0;
  }
  *(ushort4*)&vsT[((size_t)b * 32 + h) * S_ + s0] = ov;
}

// ---------------------------------------------------------------------------
// Pass 2 (2 t-tiles/wave): h1[t,h] = sum_s exp(q_t.k_s) * vs[s,h].
// ---------------------------------------------------------------------------
__global__ __launch_bounds__(256) void attn_mfma(
    const ushort* __restrict__ qb, const ushort* __restrict__ kb,
    const ushort* __restrict__ vsT, ushort* __restrict__ h1p) {
  __shared__ __align__(16) ushort sK[4 * 32 * 8];  // [hslot][s][8]
  __shared__ __align__(16) ushort sV[4 * 32 * 8];  // [sslot][h][8]
  const int tid = threadIdx.x;
  const int lane = tid & 63;
  const int lo = lane & 31, hi = lane >> 5;
  const int w = tid >> 6;
  const int b = blockIdx.y;
  const int t0 = blockIdx.x * 256 + w * 32;
  const int t1 = t0 + 128;
  const int spart = blockIdx.z;

  const ushort* qrow0 = qb + ((size_t)b * T_ + t0 + lo) * 32;
  bf16x8 q0 = pun(*(const int4*)(qrow0 + hi * 8));
  bf16x8 q1 = pun(*(const int4*)(qrow0 + 16 + hi * 8));
  const ushort* qrow1 = qb + ((size_t)b * T_ + t1 + lo) * 32;
  bf16x8 q2 = pun(*(const int4*)(qrow1 + hi * 8));
  bf16x8 q3 = pun(*(const int4*)(qrow1 + 16 + hi * 8));

  f32x16 hacc = {};
  f32x16 hacc2 = {};
  for (int sc = 0; sc < 16; ++sc) {
    const int sbase = spart * 512 + sc * 32;
    if (tid < 128) {
      int s = tid >> 2, j = tid & 3;
      *(int4*)&sK[j * 256 + s * 8] =
          *(const int4*)(kb + ((size_t)b * S_ + sbase + s) * 32 + j * 8);
    } else {
      int i2 = tid - 128;
      int h = i2 >> 2, q = i2 & 3;
      *(int4*)&sV[q * 256 + h * 8] =
          *(const int4*)(vsT + ((size_t)b * 32 + h) * S_ + sbase + q * 8);
    }
    __syncthreads();
    bf16x8 ka = pun(*(const int4*)&sK[hi * 256 + lo * 8]);
    bf16x8 kc = pun(*(const int4*)&sK[(2 + hi) * 256 + lo * 8]);
    bf16x8 va = pun(*(const int4*)&sV[hi * 256 + lo * 8]);
    bf16x8 vc = pun(*(const int4*)&sV[(2 + hi) * 256 + lo * 8]);
    // ---- tile 0 ----
    {
      f32x16 c = {};
      c = mfma32(ka, q0, c);
      c = mfma32(kc, q1, c);
      uint pk[8];
#pragma unroll
      for (int m = 0; m < 8; ++m) {
        float plo = __expf(c[2 * m]);
        float phi = __expf(c[2 * m + 1]);
        pk[m] = cvtpk(plo, phi);
      }
      asm("v_permlane32_swap_b32 %0, %1" : "+v"(pk[0]), "+v"(pk[2]));
      asm("v_permlane32_swap_b32 %0, %1" : "+v"(pk[1]), "+v"(pk[3]));
      asm("v_permlane32_swap_b32 %0, %1" : "+v"(pk[4]), "+v"(pk[6]));
      asm("v_permlane32_swap_b32 %0, %1" : "+v"(pk[5]), "+v"(pk[7]));
      int4 f0 = make_int4(pk[0], pk[1], pk[2], pk[3]);
      int4 f1 = make_int4(pk[4], pk[5], pk[6], pk[7]);
      hacc = mfma32(pun(f0), va, hacc);
      hacc = mfma32(pun(f1), vc, hacc);
    }
    // ---- tile 1 (same staged K/V) ----
    {
      f32x16 c = {};
      c = mfma32(ka, q2, c);
      c = mfma32(kc, q3, c);
      uint pk[8];
#pragma unroll
      for (int m = 0; m < 8; ++m) {
        float plo = __expf(c[2 * m]);
        float phi = __expf(c[2 * m + 1]);
        pk[m] = cvtpk(plo, phi);
      }
      asm("v_permlane32_swap_b32 %0, %1" : "+v"(pk[0]), "+v"(pk[2]));
      asm("v_permlane32_swap_b32 %0, %1" : "+v"(pk[1]), "+v"(pk[3]));
      asm("v_permlane32_swap_b32 %0, %1" : "+v"(pk[4]), "+v"(pk[6]));
      asm("v_permlane32_swap_b32 %0, %1" : "+v"(pk[5]), "+v"(pk[7]));
      int4 f0 = make_int4(pk[0], pk[1], pk[2], pk[3]);
      int4 f1 = make_int4(pk[4], pk[5], pk[6], pk[7]);
      hacc2 = mfma32(pun(f0), va, hacc2);
      hacc2 = mfma32(pun(f1), vc, hacc2);
    }
    __syncthreads();
  }
  ushort* o = h1p + (size_t)spart * QN32_ + (size_t)b * T_ * 32;
#pragma unroll
  for (int r = 0; r < 16; ++r) {
    int rr = (r & 3) + 8 * (r >> 2) + 4 * hi;
    o[(size_t)(t0 + rr) * 32 + lo] = f2bf(hacc[r]);
    o[(size_t)(t1 + rr) * 32 + lo] = f2bf(hacc2[r]);
  }
}

// ---------------------------------------------------------------------------
// K4: out[r][d] = sum_h h1[r][h] * wh[h][d]; folds 4 bf16 s-part partials.
// NON-TEMPORAL stores for out (never re-read) -> keep fp32 inputs L3-hot.
// ---------------------------------------------------------------------------
__global__ __launch_bounds__(256) void out_kernel(const ushort* __restrict__ h1p,
                                                  const float* __restrict__ wh,
                                                  float* __restrict__ out) {
  __shared__ __align__(16) float s_h1[16 * 24];
  const int tid = threadIdx.x;
  const long rbase = (long)blockIdx.x * 16;
  if (tid < 48) {
    const int r = tid / 3, c8 = tid - 3 * r;  // cols [8c8, 8c8+8) < 24
    float s[8] = {0.f, 0.f, 0.f, 0.f, 0.f, 0.f, 0.f, 0.f};
#pragma unroll
    for (int part = 0; part < 4; ++part) {
      int4 v = *(const int4*)&h1p[(size_t)part * QN32_ +
                                  (size_t)(rbase + r) * 32 + c8 * 8];
      const ushort* u = (const ushort*)&v;
#pragma unroll
      for (int j = 0; j < 8; ++j) s[j] += bf2f(u[j]);
    }
#pragma unroll
    for (int j = 0; j < 8; ++j) s_h1[r * 24 + c8 * 8 + j] = s[j];
  }
  __syncthreads();
  for (int c = 0; c < 4; ++c) {
    const int dd = c * 256 + tid;
    float wr[24];
#pragma unroll
    for (int h = 0; h < 24; ++h) wr[h] = wh[h * D_ + dd];
#pragma unroll 1
    for (int r = 0; r < 16; ++r) {
      float a = 0.f;
#pragma unroll
      for (int j = 0; j < 6; ++j) {
        float4 hv = *(const float4*)(s_h1 + r * 24 + 4 * j);
        a = fmaf(hv.x, wr[4 * j], a);
        a = fmaf(hv.y, wr[4 * j + 1], a);
        a = fmaf(hv.z, wr[4 * j + 2], a);
        a = fmaf(hv.w, wr[4 * j + 3], a);
      }
      __builtin_nontemporal_store(a, &out[(rbase + r) * D_ + dd]);
    }
  }
}

// ---------------------------------------------------------------------------
extern "C" void kernel_launch(void* const* d_in, const int* in_sizes, int n_in,
                              void* d_out, int out_size, void* d_ws,
                              size_t ws_size, hipStream_t stream) {
  const float* encoded = (const float*)d_in[0];
  const float* text = (const float*)d_in[1];
  const float* wq = (const float*)d_in[2];
  const float* wk = (const float*)d_in[3];
  const float* wv = (const float*)d_in[4];
  const float* wh = (const float*)d_in[5];
  float* out = (float*)d_out;

  // workspace layout: ~17.7 MiB total
  ushort* qb = (ushort*)d_ws;               // [B][T][32] bf16  (2 MiB)
  ushort* kbuf = qb + QN32_;                // [B][S][32] bf16  (2 MiB)
  float* vv = (float*)(kbuf + QN32_);       // [B][S][24] f32   (3 MiB)
  float* dpart = vv + (size_t)BS_ * H_;     // [4][B*S] f32     (0.5 MiB)
  ushort* vsT = (ushort*)(dpart + 4 * BS_); // [B][32][S] bf16  (2 MiB)
  ushort* h1p = vsT + (size_t)B_ * 32 * S_; // [4][B][T][32] bf16 (8 MiB)
  ushort* wpk = h1p + 4 * QN32_;            // [3][128][24][8] bf16 (144 KiB)

  prep_w<<<36, 256, 0, stream>>>(wq, wk, wv, wpk);
  proj_q<<<1024, 256, 0, stream>>>(text, wpk, qb);
  proj_kv<<<1024, 256, 0, stream>>>(encoded, wpk, kbuf, vv);
  colsum_mfma<<<dim3(S_ / 256, B_, 4), 256, 0, stream>>>(qb, kbuf, dpart);
  vscale_kernel<<<(B_ * 32 * (S_ / 4)) / 256, 256, 0, stream>>>(vv, dpart, vsT);
  attn_mfma<<<dim3(T_ / 256, B_, 4), 256, 0, stream>>>(qb, kbuf, vsT, h1p);
  out_kernel<<<NROW_ / 16, 256, 0, stream>>>(h1p, wh, out);
}

// Round 14
// 135.401 us; speedup vs baseline: 1.0084x; 1.0084x over previous
//
#include <hip/hip_runtime.h>
#include <hip/hip_bf16.h>

// Problem: B=16, T=S=2048, D=1024, H=24
#define B_ 16
#define T_ 2048
#define S_ 2048
#define D_ 1024
#define H_ 24
#define NROW_ (B_ * T_)            // 32768 rows
#define BS_ (B_ * S_)              // 32768
#define QN32_ ((size_t)NROW_ * 32) // padded projection / h1-part elements

typedef float f32x16 __attribute__((ext_vector_type(16)));
typedef __bf16 bf16x8 __attribute__((ext_vector_type(8)));

union B8u { int4 i; bf16x8 b; };
__device__ inline bf16x8 pun(int4 v) { B8u u; u.i = v; return u.b; }

__device__ inline ushort f2bf(float f) {  // RNE fp32->bf16
  uint u = __float_as_uint(f);
  u += 0x7fffu + ((u >> 16) & 1u);
  return (ushort)(u >> 16);
}
__device__ inline float bf2f(ushort u) { return __uint_as_float(((uint)u) << 16); }

__device__ inline f32x16 mfma32(bf16x8 a, bf16x8 b, f32x16 c) {
  return __builtin_amdgcn_mfma_f32_32x32x16_bf16(a, b, c, 0, 0, 0);
}

__device__ inline uint cvtpk(float a, float b) {
  uint r;
  asm("v_cvt_pk_bf16_f32 %0, %1, %2" : "=v"(r) : "v"(a), "v"(b));
  return r;
}

// ---------------------------------------------------------------------------
// prep_w: pack wq,wk,wv -> global fragment-order bf16 wpk[3][128][24][8].
// ---------------------------------------------------------------------------
__global__ __launch_bounds__(256) void prep_w(
    const float* __restrict__ wq, const float* __restrict__ wk,
    const float* __restrict__ wv, ushort* __restrict__ wpk) {
  int i = blockIdx.x * 256 + threadIdx.x;  // < 3*128*24 = 9216
  if (i >= 3 * 128 * H_) return;
  int which = i / (128 * H_);
  int rem = i - which * 128 * H_;
  int k8g = rem / H_, n = rem - k8g * H_;
  const float* w = (which == 0) ? wq : (which == 1) ? wk : wv;
  ushort t[8];
#pragma unroll
  for (int j = 0; j < 8; ++j) t[j] = f2bf(w[(k8g * 8 + j) * H_ + n]);
  *(int4*)&wpk[(size_t)i * 8] = *(const int4*)t;
}

// ---------------------------------------------------------------------------
// proj_qkv (R13): single 2048-block dispatch, INTERLEAVED roles.
//   blockIdx.x & 1 == 0: text row-block -> qb
//   blockIdx.x & 1 == 1: encoded row-block -> kbuf + vv
// Rationale: per-CU outstanding-line cap (~2.8 TB/s read, confirmed by 5
// schedule-null experiments R7-R12) means schedules can't help; the last
// lever is removing the serial launch boundary + ramp tails between the two
// proj kernels so both input streams flow for the whole dispatch.
// Staging = R12 one-shot max-depth (32 row-loads back-to-back, 1KB runs),
// swizzled wave-private LDS slab, pure-LDS MFMA pass, padded cross-wave
// reduce. No R8 regalloc trap: no K-loop, gv dies at WRITEALL, bfr liveness
// short. LDS 64KB -> 2 blocks/CU.
// ---------------------------------------------------------------------------
__global__ __launch_bounds__(256, 2) void proj_qkv(
    const float* __restrict__ text, const float* __restrict__ encoded,
    const ushort* __restrict__ wpk, ushort* __restrict__ qb,
    ushort* __restrict__ kbuf, float* __restrict__ vv) {
  __shared__ __align__(16) ushort sA[4][32][256];  // 64 KiB wave-private bf16

  const int tid = threadIdx.x;
  const int lane = tid & 63, lo = lane & 31, hi = lane >> 5, w = tid >> 6;
  const int l = lane;
  const bool kvmode = (blockIdx.x & 1);
  const int rblk = blockIdx.x >> 1;                    // 0..1023
  const int bid = (rblk & 7) * 128 + (rblk >> 3);      // XCD swizzle
  const long rowbase = (long)bid * 32;
  const int ne = (lo < H_) ? lo : 0;
  const float* in = kvmode ? encoded : text;
  const float* rowp = in + rowbase * D_ + w * 256;

  // ---- one-shot staging: all 32 row-loads in flight, then write pass ----
  float4 gv[32];
#pragma unroll
  for (int r = 0; r < 32; ++r)
    gv[r] = *(const float4*)(rowp + (size_t)r * D_ + l * 4);
#pragma unroll
  for (int r = 0; r < 32; ++r) {
    uint p0 = cvtpk(gv[r].x, gv[r].y), p1 = cvtpk(gv[r].z, gv[r].w);
    const int s = (l >> 1) ^ (r & 7);
    *(uint2*)&sA[w][r][s * 8 + (l & 1) * 4] = make_uint2(p0, p1);
  }

  // ---- B-fragments (L2-hot) + pure-LDS MFMA pass ----
  const ushort* wp1 = wpk + (size_t)(kvmode ? 1 : 0) * 128 * H_ * 8;
  const ushort* wp2 = wpk + (size_t)2 * 128 * H_ * 8;  // wv (kv only)
  f32x16 acc = {};
  f32x16 acc2 = {};
  if (kvmode) {
#pragma unroll
    for (int c = 0; c < 16; ++c) {
      const int k8g = w * 32 + 2 * c + hi;
      int4 b1 = *(const int4*)&wp1[(size_t)(k8g * H_ + ne) * 8];
      int4 b2 = *(const int4*)&wp2[(size_t)(k8g * H_ + ne) * 8];
      const int s = (2 * c + hi) ^ (lo & 7);
      bf16x8 a = pun(*(const int4*)&sA[w][lo][s * 8]);
      acc = mfma32(a, pun(b1), acc);
      acc2 = mfma32(a, pun(b2), acc2);
    }
  } else {
#pragma unroll
    for (int c = 0; c < 16; ++c) {
      const int k8g = w * 32 + 2 * c + hi;
      int4 b1 = *(const int4*)&wp1[(size_t)(k8g * H_ + ne) * 8];
      const int s = (2 * c + hi) ^ (lo & 7);
      bf16x8 a = pun(*(const int4*)&sA[w][lo][s * 8]);
      acc = mfma32(a, pun(b1), acc);
    }
  }

  // ---- cross-wave K-partial reduce (sR aliased into sA; stride 17) ----
  float* sR = (float*)sA;
  __syncthreads();
#pragma unroll
  for (int r = 0; r < 16; ++r) sR[w * 1088 + lane * 17 + r] = acc[r];
  __syncthreads();
  {
    const int qd = tid >> 6, l2 = tid & 63, lo2 = l2 & 31, hi2 = l2 >> 5;
    ushort* o1 = kvmode ? kbuf : qb;
#pragma unroll
    for (int rr = 0; rr < 4; ++rr) {
      const int r = qd * 4 + rr;
      float s = sR[0 * 1088 + l2 * 17 + r] + sR[1 * 1088 + l2 * 17 + r] +
                sR[2 * 1088 + l2 * 17 + r] + sR[3 * 1088 + l2 * 17 + r];
      const int mrow = rr + 8 * qd + 4 * hi2;
      o1[(size_t)(rowbase + mrow) * 32 + lo2] =
          (lo2 < H_) ? f2bf(s) : (ushort)0;
    }
  }
  if (kvmode) {
    __syncthreads();  // WAR on sR
#pragma unroll
    for (int r = 0; r < 16; ++r) sR[w * 1088 + lane * 17 + r] = acc2[r];
    __syncthreads();
    const int qd = tid >> 6, l2 = tid & 63, lo2 = l2 & 31, hi2 = l2 >> 5;
    if (lo2 < H_) {
#pragma unroll
      for (int rr = 0; rr < 4; ++rr) {
        const int r = qd * 4 + rr;
        float s = sR[0 * 1088 + l2 * 17 + r] + sR[1 * 1088 + l2 * 17 + r] +
                  sR[2 * 1088 + l2 * 17 + r] + sR[3 * 1088 + l2 * 17 + r];
        const int mrow = rr + 8 * qd + 4 * hi2;
        vv[(size_t)(rowbase + mrow) * H_ + lo2] = s;
      }
    }
  }
}

// ---------------------------------------------------------------------------
// Pass 1 (2 s-tiles/wave): d[b,s] = sum_t exp(q_t.k_s).
// ---------------------------------------------------------------------------
__global__ __launch_bounds__(256) void colsum_mfma(
    const ushort* __restrict__ qb, const ushort* __restrict__ kb,
    float* __restrict__ dpart) {
  __shared__ __align__(16) ushort sQ[4 * 32 * 8];  // [hslot][t][8]
  const int tid = threadIdx.x;
  const int lane = tid & 63;
  const int lo = lane & 31, hi = lane >> 5;
  const int w = tid >> 6;
  const int b = blockIdx.y;
  const int s0 = blockIdx.x * 256 + w * 32;
  const int s1 = s0 + 128;
  const int tpart = blockIdx.z;

  const ushort* krow0 = kb + ((size_t)b * S_ + s0 + lo) * 32;
  bf16x8 k0 = pun(*(const int4*)(krow0 + hi * 8));
  bf16x8 k1 = pun(*(const int4*)(krow0 + 16 + hi * 8));
  const ushort* krow1 = kb + ((size_t)b * S_ + s1 + lo) * 32;
  bf16x8 k2 = pun(*(const int4*)(krow1 + hi * 8));
  bf16x8 k3 = pun(*(const int4*)(krow1 + 16 + hi * 8));

  float dl = 0.f, dl2 = 0.f;
  for (int tc = 0; tc < 16; ++tc) {
    const int tbase = tpart * 512 + tc * 32;
    if (tid < 128) {
      int t = tid >> 2, j = tid & 3;
      *(int4*)&sQ[j * 256 + t * 8] =
          *(const int4*)(qb + ((size_t)b * T_ + tbase + t) * 32 + j * 8);
    }
    __syncthreads();
    bf16x8 qa = pun(*(const int4*)&sQ[hi * 256 + lo * 8]);
    bf16x8 qc = pun(*(const int4*)&sQ[(2 + hi) * 256 + lo * 8]);
    f32x16 c = {};
    c = mfma32(qa, k0, c);
    c = mfma32(qc, k1, c);
#pragma unroll
    for (int r = 0; r < 16; ++r) dl += __expf(c[r]);
    f32x16 c2 = {};
    c2 = mfma32(qa, k2, c2);
    c2 = mfma32(qc, k3, c2);
#pragma unroll
    for (int r = 0; r < 16; ++r) dl2 += __expf(c2[r]);
    __syncthreads();
  }
  dl += __shfl_xor(dl, 32);
  dl2 += __shfl_xor(dl2, 32);
  if (hi == 0) {
    dpart[(size_t)tpart * BS_ + (size_t)b * S_ + s0 + lo] = dl;
    dpart[(size_t)tpart * BS_ + (size_t)b * S_ + s1 + lo] = dl2;
  }
}

// ---------------------------------------------------------------------------
// vscale (dpart reduce folded in): vsT[b][h][s] = bf16(v * 1/d), h pad 32.
// ---------------------------------------------------------------------------
__global__ __launch_bounds__(256) void vscale_kernel(
    const float* __restrict__ vv, const float* __restrict__ dpart,
    ushort* __restrict__ vsT) {
  int gid = blockIdx.x * 256 + threadIdx.x;  // < 16*32*512
  int s4 = gid & 511;
  int h = (gid >> 9) & 31;
  int b = gid >> 14;
  int s0 = s4 * 4;
  ushort4 ov;
  if (h < H_) {
    const float* vp = vv + ((size_t)b * S_ + s0) * H_ + h;
    const float* dp = dpart + (size_t)b * S_ + s0;
    float dv[4];
#pragma unroll
    for (int i = 0; i < 4; ++i) {
      float d = dp[i] + dp[BS_ + i] + dp[2 * BS_ + i] + dp[3 * BS_ + i];
      dv[i] = 1.0f / d;
    }
    ov.x = f2bf(vp[0 * H_] * dv[0]);
    ov.y = f2bf(vp[1 * H_] * dv[1]);
    ov.z = f2bf(vp[2 * H_] * dv[2]);
    ov.w = f2bf(vp[3 * H_] * dv[3]);
  } else {
    ov.x = ov.y = ov.z = ov.w = 0;
  }
  *(ushort4*)&vsT[((size_t)b * 32 + h) * S_ + s0] = ov;
}

// ---------------------------------------------------------------------------
// Pass 2 (2 t-tiles/wave): h1[t,h] = sum_s exp(q_t.k_s) * vs[s,h].
// ---------------------------------------------------------------------------
__global__ __launch_bounds__(256) void attn_mfma(
    const ushort* __restrict__ qb, const ushort* __restrict__ kb,
    const ushort* __restrict__ vsT, ushort* __restrict__ h1p) {
  __shared__ __align__(16) ushort sK[4 * 32 * 8];  // [hslot][s][8]
  __shared__ __align__(16) ushort sV[4 * 32 * 8];  // [sslot][h][8]
  const int tid = threadIdx.x;
  const int lane = tid & 63;
  const int lo = lane & 31, hi = lane >> 5;
  const int w = tid >> 6;
  const int b = blockIdx.y;
  const int t0 = blockIdx.x * 256 + w * 32;
  const int t1 = t0 + 128;
  const int spart = blockIdx.z;

  const ushort* qrow0 = qb + ((size_t)b * T_ + t0 + lo) * 32;
  bf16x8 q0 = pun(*(const int4*)(qrow0 + hi * 8));
  bf16x8 q1 = pun(*(const int4*)(qrow0 + 16 + hi * 8));
  const ushort* qrow1 = qb + ((size_t)b * T_ + t1 + lo) * 32;
  bf16x8 q2 = pun(*(const int4*)(qrow1 + hi * 8));
  bf16x8 q3 = pun(*(const int4*)(qrow1 + 16 + hi * 8));

  f32x16 hacc = {};
  f32x16 hacc2 = {};
  for (int sc = 0; sc < 16; ++sc) {
    const int sbase = spart * 512 + sc * 32;
    if (tid < 128) {
      int s = tid >> 2, j = tid & 3;
      *(int4*)&sK[j * 256 + s * 8] =
          *(const int4*)(kb + ((size_t)b * S_ + sbase + s) * 32 + j * 8);
    } else {
      int i2 = tid - 128;
      int h = i2 >> 2, q = i2 & 3;
      *(int4*)&sV[q * 256 + h * 8] =
          *(const int4*)(vsT + ((size_t)b * 32 + h) * S_ + sbase + q * 8);
    }
    __syncthreads();
    bf16x8 ka = pun(*(const int4*)&sK[hi * 256 + lo * 8]);
    bf16x8 kc = pun(*(const int4*)&sK[(2 + hi) * 256 + lo * 8]);
    bf16x8 va = pun(*(const int4*)&sV[hi * 256 + lo * 8]);
    bf16x8 vc = pun(*(const int4*)&sV[(2 + hi) * 256 + lo * 8]);
    // ---- tile 0 ----
    {
      f32x16 c = {};
      c = mfma32(ka, q0, c);
      c = mfma32(kc, q1, c);
      uint pk[8];
#pragma unroll
      for (int m = 0; m < 8; ++m) {
        float plo = __expf(c[2 * m]);
        float phi = __expf(c[2 * m + 1]);
        pk[m] = cvtpk(plo, phi);
      }
      asm("v_permlane32_swap_b32 %0, %1" : "+v"(pk[0]), "+v"(pk[2]));
      asm("v_permlane32_swap_b32 %0, %1" : "+v"(pk[1]), "+v"(pk[3]));
      asm("v_permlane32_swap_b32 %0, %1" : "+v"(pk[4]), "+v"(pk[6]));
      asm("v_permlane32_swap_b32 %0, %1" : "+v"(pk[5]), "+v"(pk[7]));
      int4 f0 = make_int4(pk[0], pk[1], pk[2], pk[3]);
      int4 f1 = make_int4(pk[4], pk[5], pk[6], pk[7]);
      hacc = mfma32(pun(f0), va, hacc);
      hacc = mfma32(pun(f1), vc, hacc);
    }
    // ---- tile 1 (same staged K/V) ----
    {
      f32x16 c = {};
      c = mfma32(ka, q2, c);
      c = mfma32(kc, q3, c);
      uint pk[8];
#pragma unroll
      for (int m = 0; m < 8; ++m) {
        float plo = __expf(c[2 * m]);
        float phi = __expf(c[2 * m + 1]);
        pk[m] = cvtpk(plo, phi);
      }
      asm("v_permlane32_swap_b32 %0, %1" : "+v"(pk[0]), "+v"(pk[2]));
      asm("v_permlane32_swap_b32 %0, %1" : "+v"(pk[1]), "+v"(pk[3]));
      asm("v_permlane32_swap_b32 %0, %1" : "+v"(pk[4]), "+v"(pk[6]));
      asm("v_permlane32_swap_b32 %0, %1" : "+v"(pk[5]), "+v"(pk[7]));
      int4 f0 = make_int4(pk[0], pk[1], pk[2], pk[3]);
      int4 f1 = make_int4(pk[4], pk[5], pk[6], pk[7]);
      hacc2 = mfma32(pun(f0), va, hacc2);
      hacc2 = mfma32(pun(f1), vc, hacc2);
    }
    __syncthreads();
  }
  ushort* o = h1p + (size_t)spart * QN32_ + (size_t)b * T_ * 32;
#pragma unroll
  for (int r = 0; r < 16; ++r) {
    int rr = (r & 3) + 8 * (r >> 2) + 4 * hi;
    o[(size_t)(t0 + rr) * 32 + lo] = f2bf(hacc[r]);
    o[(size_t)(t1 + rr) * 32 + lo] = f2bf(hacc2[r]);
  }
}

// ---------------------------------------------------------------------------
// K4: out[r][d] = sum_h h1[r][h] * wh[h][d]; folds 4 bf16 s-part partials.
// NON-TEMPORAL stores for out (never re-read) -> keep fp32 inputs L3-hot.
// ---------------------------------------------------------------------------
__global__ __launch_bounds__(256) void out_kernel(const ushort* __restrict__ h1p,
                                                  const float* __restrict__ wh,
                                                  float* __restrict__ out) {
  __shared__ __align__(16) float s_h1[16 * 24];
  const int tid = threadIdx.x;
  const long rbase = (long)blockIdx.x * 16;
  if (tid < 48) {
    const int r = tid / 3, c8 = tid - 3 * r;  // cols [8c8, 8c8+8) < 24
    float s[8] = {0.f, 0.f, 0.f, 0.f, 0.f, 0.f, 0.f, 0.f};
#pragma unroll
    for (int part = 0; part < 4; ++part) {
      int4 v = *(const int4*)&h1p[(size_t)part * QN32_ +
                                  (size_t)(rbase + r) * 32 + c8 * 8];
      const ushort* u = (const ushort*)&v;
#pragma unroll
      for (int j = 0; j < 8; ++j) s[j] += bf2f(u[j]);
    }
#pragma unroll
    for (int j = 0; j < 8; ++j) s_h1[r * 24 + c8 * 8 + j] = s[j];
  }
  __syncthreads();
  for (int c = 0; c < 4; ++c) {
    const int dd = c * 256 + tid;
    float wr[24];
#pragma unroll
    for (int h = 0; h < 24; ++h) wr[h] = wh[h * D_ + dd];
#pragma unroll 1
    for (int r = 0; r < 16; ++r) {
      float a = 0.f;
#pragma unroll
      for (int j = 0; j < 6; ++j) {
        float4 hv = *(const float4*)(s_h1 + r * 24 + 4 * j);
        a = fmaf(hv.x, wr[4 * j], a);
        a = fmaf(hv.y, wr[4 * j + 1], a);
        a = fmaf(hv.z, wr[4 * j + 2], a);
        a = fmaf(hv.w, wr[4 * j + 3], a);
      }
      __builtin_nontemporal_store(a, &out[(rbase + r) * D_ + dd]);
    }
  }
}

// ---------------------------------------------------------------------------
extern "C" void kernel_launch(void* const* d_in, const int* in_sizes, int n_in,
                              void* d_out, int out_size, void* d_ws,
                              size_t ws_size, hipStream_t stream) {
  const float* encoded = (const float*)d_in[0];
  const float* text = (const float*)d_in[1];
  const float* wq = (const float*)d_in[2];
  const float* wk = (const float*)d_in[3];
  const float* wv = (const float*)d_in[4];
  const float* wh = (const float*)d_in[5];
  float* out = (float*)d_out;

  // workspace layout: ~17.7 MiB total
  ushort* qb = (ushort*)d_ws;               // [B][T][32] bf16  (2 MiB)
  ushort* kbuf = qb + QN32_;                // [B][S][32] bf16  (2 MiB)
  float* vv = (float*)(kbuf + QN32_);       // [B][S][24] f32   (3 MiB)
  float* dpart = vv + (size_t)BS_ * H_;     // [4][B*S] f32     (0.5 MiB)
  ushort* vsT = (ushort*)(dpart + 4 * BS_); // [B][32][S] bf16  (2 MiB)
  ushort* h1p = vsT + (size_t)B_ * 32 * S_; // [4][B][T][32] bf16 (8 MiB)
  ushort* wpk = h1p + 4 * QN32_;            // [3][128][24][8] bf16 (144 KiB)

  prep_w<<<36, 256, 0, stream>>>(wq, wk, wv, wpk);
  proj_qkv<<<2048, 256, 0, stream>>>(text, encoded, wpk, qb, kbuf, vv);
  colsum_mfma<<<dim3(S_ / 256, B_, 4), 256, 0, stream>>>(qb, kbuf, dpart);
  vscale_kernel<<<(B_ * 32 * (S_ / 4)) / 256, 256, 0, stream>>>(vv, dpart, vsT);
  attn_mfma<<<dim3(T_ / 256, B_, 4), 256, 0, stream>>>(qb, kbuf, vsT, h1p);
  out_kernel<<<NROW_ / 16, 256, 0, stream>>>(h1p, wh, out);
}